// Round 2
// baseline (36.457 us; speedup 1.0000x reference)
//
#include <hip/hip_runtime.h>
#include <hip/hip_bf16.h>

// Masked one-hot: out[b,n,c] = (labels[b,n] == c) ? 1.0f : 0.0f; rows with
// label < 0 stay all-zero (negative label never equals a column index).
// Write-bound: 79.6 MB out. Empirical write ceiling on this chip: 7.0 TB/s
// (harness fillBuffer). Strategy: 16 floats (64 B) per thread -> 1 division
// + 2 label loads per 4 float4 stores, minimizing VALU per byte stored.

#define BB 256
#define NN 128
#define CC 607
#define TOTAL (BB * NN * CC)        // 19,890,176 = 2^15 * 607, divisible by 16
#define PER_THREAD 16
#define NTHREADS (TOTAL / PER_THREAD)  // 1,243,136 = 4856 * 256 exactly

__global__ __launch_bounds__(256) void onehot16_kernel(const int* __restrict__ labels,
                                                       float* __restrict__ out) {
    int t = blockIdx.x * blockDim.x + threadIdx.x;  // exact-fit grid, no bounds check
    int base = t * PER_THREAD;                      // < 2^25, int-safe

    // A 16-element chunk spans at most rows row0 and row0+1 (16 < CC).
    unsigned row0 = (unsigned)base / (unsigned)CC;  // magic-mul division (once)
    int c0 = base - (int)row0 * CC;
    unsigned row1 = row0 + 1;
    if (row1 >= BB * NN) row1 = BB * NN - 1;        // clamp last chunk's spill read
    int lab0 = labels[row0];                        // L1-broadcast across lanes
    int lab1 = labels[row1];

    float4 v[4];
    float* vp = reinterpret_cast<float*>(v);
#pragma unroll
    for (int j = 0; j < PER_THREAD; ++j) {          // fully unrolled, static idx
        int c = c0 + j;
        bool wrap = (c >= CC);
        int cc = wrap ? c - CC : c;
        int lab = wrap ? lab1 : lab0;
        vp[j] = (cc == lab) ? 1.0f : 0.0f;          // negative lab never matches
    }

    float4* o = reinterpret_cast<float4*>(out + base);  // 64B-aligned
#pragma unroll
    for (int k = 0; k < 4; ++k) o[k] = v[k];
}

extern "C" void kernel_launch(void* const* d_in, const int* in_sizes, int n_in,
                              void* d_out, int out_size, void* d_ws, size_t ws_size,
                              hipStream_t stream) {
    // d_in[0] = obj_sem_cls_pred (unused), d_in[1] = obj_labels (int32 on device),
    // d_in[2] = cur_step, d_in[3] = total_steps (unused).
    const int* labels = (const int*)d_in[1];
    float* out = (float*)d_out;

    const int block = 256;
    const int grid = NTHREADS / block;  // 4856, exact fit
    onehot16_kernel<<<grid, block, 0, stream>>>(labels, out);
}

// Round 3
// 18.616 us; speedup vs baseline: 1.9584x; 1.9584x over previous
//
#include <hip/hip_runtime.h>
#include <hip/hip_bf16.h>

// Masked one-hot, decomposed as: (1) zero-fill 79.6 MB at the measured
// write ceiling (~7.0 TB/s, per the harness's fillBufferAligned on this
// chip), (2) scatter <=32768 ones at out[row*607 + label] for label>=0.
//
// R2 lesson: per-thread 64B chunks break inter-lane coalescing (2x
// regression). Here every store instruction is inter-lane contiguous:
// fill store k of a block covers bytes [blk*16KB + k*4KB + lane*16 ...).

#define BB 256
#define NN 128
#define CC 607
#define TOTAL (BB * NN * CC)          // 19,890,176 floats = 4,972,544 float4
#define NV4   (TOTAL / 4)             // 4,972,544 = 4856 * 1024 exactly

__global__ __launch_bounds__(256) void fill_zero_kernel(float4* __restrict__ out) {
    const float4 z = make_float4(0.f, 0.f, 0.f, 0.f);
    int base = blockIdx.x * 1024 + threadIdx.x;  // float4 units; block spans 16 KB
    out[base]       = z;   // each store: lanes contiguous (16 B/lane)
    out[base + 256] = z;
    out[base + 512] = z;
    out[base + 768] = z;
}

__global__ __launch_bounds__(256) void scatter_ones_kernel(const int* __restrict__ labels,
                                                           float* __restrict__ out) {
    int t = blockIdx.x * 256 + threadIdx.x;      // exact fit: 128 blocks * 256 = 32768
    int lab = labels[t];                         // coalesced dword load
    if (lab >= 0)
        out[t * CC + lab] = 1.0f;                // scattered 4B store, ~1/608 inactive
}

extern "C" void kernel_launch(void* const* d_in, const int* in_sizes, int n_in,
                              void* d_out, int out_size, void* d_ws, size_t ws_size,
                              hipStream_t stream) {
    // d_in[0] = obj_sem_cls_pred (unused), d_in[1] = obj_labels (int32 on device),
    // d_in[2] = cur_step, d_in[3] = total_steps (unused).
    const int* labels = (const int*)d_in[1];
    float* out = (float*)d_out;

    fill_zero_kernel<<<NV4 / 1024, 256, 0, stream>>>((float4*)out);     // 4856 blocks
    scatter_ones_kernel<<<(BB * NN) / 256, 256, 0, stream>>>(labels, out); // 128 blocks
}

// Round 4
// 16.934 us; speedup vs baseline: 2.1529x; 1.0993x over previous
//
#include <hip/hip_runtime.h>
#include <hip/hip_bf16.h>

// Masked one-hot, single fused kernel with block-region ownership:
//   phase 1: each block zero-fills its exclusive 16 KB region using the
//            exact rocclr fillBuffer store pattern (4x float4/thread,
//            4 KB stride -> every store inter-lane contiguous, ~7 TB/s).
//   __syncthreads() (emits s_waitcnt vmcnt(0) before s_barrier on gfx950,
//            so the region's zeros are globally visible).
//   phase 2: threads 0..7 probe the <=8 rows overlapping this region and
//            write 1.0f at row*607+label IFF it lies inside the region
//            (exactly-once across blocks; same-block store ordering).
// R2 lesson: inter-lane contiguity per store instruction is mandatory.
// R3 lesson: a second dispatch costs ~7 us (latency tail + graph gap).

#define BB 256
#define NN 128
#define CC 607
#define NROWS (BB * NN)               // 32768
#define TOTAL (NROWS * CC)            // 19,890,176 floats
#define NV4   (TOTAL / 4)             // 4,972,544 = 4856 * 1024 exactly
#define NBLOCKS (NV4 / 1024)          // 4856; each block owns 4096 floats (16 KB)

__global__ __launch_bounds__(256) void onehot_fused_kernel(const int* __restrict__ labels,
                                                           float* __restrict__ out) {
    const int b = blockIdx.x;
    const int tid = threadIdx.x;

    // ---- phase 1: zero-fill own region (memset-identical pattern) ----
    float4* o4 = reinterpret_cast<float4*>(out) + b * 1024 + tid;
    const float4 z = make_float4(0.f, 0.f, 0.f, 0.f);
    o4[0]   = z;
    o4[256] = z;
    o4[512] = z;
    o4[768] = z;

    __syncthreads();  // vmcnt(0) drain + barrier: region zeros are visible

    // ---- phase 2: set hot elements inside own region ----
    if (tid < 8) {
        const int lo = b * 4096;              // first float owned
        const int hi = lo + 4096;             // one past last
        unsigned rlo = (unsigned)lo / (unsigned)CC;   // magic-mul division
        unsigned r = rlo + tid;
        if (r < NROWS && (int)(r * CC) < hi) {        // row starts before region end
            int lab = labels[r];
            if (lab >= 0) {
                int flat = (int)(r * CC) + lab;
                if (flat >= lo && flat < hi)          // exclusive ownership
                    out[flat] = 1.0f;
            }
        }
    }
}

extern "C" void kernel_launch(void* const* d_in, const int* in_sizes, int n_in,
                              void* d_out, int out_size, void* d_ws, size_t ws_size,
                              hipStream_t stream) {
    // d_in[0] = obj_sem_cls_pred (unused), d_in[1] = obj_labels (int32 on device),
    // d_in[2] = cur_step, d_in[3] = total_steps (unused).
    const int* labels = (const int*)d_in[1];
    float* out = (float*)d_out;

    onehot_fused_kernel<<<NBLOCKS, 256, 0, stream>>>(labels, out);
}